// Round 2
// baseline (443.339 us; speedup 1.0000x reference)
//
#include <hip/hip_runtime.h>
#include <hip/hip_bf16.h>
#include <stdint.h>

// Problem constants
#define D_IN   768
#define D_EXP  3072
#define NEXP   8
#define NTOK   4096

typedef __attribute__((ext_vector_type(4))) float f32x4;
typedef __attribute__((ext_vector_type(8))) __bf16 bf16x8;

union V16 { uint4 u; bf16x8 b; };

// ---------------- workspace layout (bytes) ----------------
// xb   : 4096*768*2      = 6,291,456
// rows : 8*4096*4        =   131,072
// wts  : 8*4096*4        =   131,072
// cnt/seg small
// hbuf : 8192*3072*2     = 50,331,648   (total ~56.9 MB)
#define WS_XB    0u
#define WS_ROWS  6291456u
#define WS_WTS   6422528u
#define WS_CNT   6553600u
#define WS_SEG   6553664u
#define WS_HBUF  6554624u

static __device__ __forceinline__ unsigned short f2bf(float f) {
    unsigned u = __float_as_uint(f);
    u += 0x7fffu + ((u >> 16) & 1u);   // RNE
    return (unsigned short)(u >> 16);
}

// ---------------- routing ----------------
__global__ void route_kernel(const float* __restrict__ rw, const int* __restrict__ ei,
                             int* __restrict__ rows, float* __restrict__ wts,
                             int* __restrict__ cnt, int* __restrict__ seg) {
    __shared__ int lcnt[NEXP];
    const int t = threadIdx.x;
    if (t < NEXP) lcnt[t] = 0;
    __syncthreads();
    for (int tok = t; tok < NTOK; tok += blockDim.x) {
        int e0 = ei[2 * tok], e1 = ei[2 * tok + 1];
        float w0 = rw[2 * tok], w1 = rw[2 * tok + 1];
        if (e0 == e1) w0 += w1;
        int p0 = atomicAdd(&lcnt[e0], 1);
        rows[(e0 << 12) + p0] = tok; wts[(e0 << 12) + p0] = w0;
        if (e1 != e0) {
            int p1 = atomicAdd(&lcnt[e1], 1);
            rows[(e1 << 12) + p1] = tok; wts[(e1 << 12) + p1] = w1;
        }
    }
    __syncthreads();
    if (t == 0) {
        int s = 0;
        for (int e = 0; e < NEXP; e++) { seg[e] = s; cnt[e] = lcnt[e]; s += lcnt[e]; }
        seg[NEXP] = s;
    }
}

// ---------------- x f32 -> bf16 ----------------
__global__ void cvt_x_kernel(const float4* __restrict__ x4, ushort4* __restrict__ xb4) {
    int i = blockIdx.x * blockDim.x + threadIdx.x;   // 786432 total, exact
    float4 v = x4[i];
    ushort4 o;
    o.x = f2bf(v.x); o.y = f2bf(v.y); o.z = f2bf(v.z); o.w = f2bf(v.w);
    xb4[i] = o;
}

// LDS tiles (both gemms):
//   A  : [128 m-rows][64 k] bf16, 128 B/row; slot s (16B) stored at s ^ (m&7).
//   B' : [128 n-rows][64 k] bf16 (transposed at staging); slot stored at s ^ ((n^(n>>3))&7).
// Fragment reads are plain ds_read_b128 of 8 contiguous k — the m91/m92-verified pattern.

// ---------------- GEMM1: h = silu(X Wg) * (X Wu), bf16 out ----------------
__global__ __launch_bounds__(512) void gemm1_kernel(
    const unsigned short* __restrict__ xb,
    const float* __restrict__ wg_all,
    const float* __restrict__ wu_all,
    const int* __restrict__ rows,
    const int* __restrict__ cnt,
    const int* __restrict__ seg,
    unsigned short* __restrict__ hbuf)
{
    __shared__ __align__(16) char smem[49664];  // A 16K | Bg 16K | Bu 16K | rows 512
    const int e = blockIdx.y >> 5;
    const int rt = blockIdx.y & 31;
    const int count = cnt[e];
    const int rbase = rt << 7;
    if (rbase >= count) return;
    const int nbase = blockIdx.x << 7;
    const int t = threadIdx.x;

    int* rows_lds = (int*)(smem + 49152);
    if (t < 128) {
        int idx = rbase + t;
        if (idx > count - 1) idx = count - 1;
        rows_lds[t] = rows[(e << 12) + idx];
    }
    __syncthreads();

    // ---- A staging addresses ----
    const int a_row = t >> 3, a_slot = t & 7;
    const unsigned short* agp0 = xb + (size_t)rows_lds[a_row] * D_IN + a_slot * 8;
    const unsigned short* agp1 = xb + (size_t)rows_lds[a_row + 64] * D_IN + a_slot * 8;
    const int aw0 = a_row * 128 + ((a_slot ^ (a_row & 7)) << 4);
    const int aw1 = (a_row + 64) * 128 + ((a_slot ^ (a_row & 7)) << 4);

    // ---- B staging addresses (register transpose) ----
    const int kq = t >> 5, bc = t & 31;          // k-quad 0..15, n-quad col base 4*bc
    const float* wgp = wg_all + (size_t)e * D_IN * D_EXP + (size_t)(4 * kq) * D_EXP + nbase + 4 * bc;
    const float* wup = wu_all + (size_t)e * D_IN * D_EXP + (size_t)(4 * kq) * D_EXP + nbase + 4 * bc;
    int bw[4];
    #pragma unroll
    for (int c = 0; c < 4; c++) {
        int n = 4 * bc + c;
        int key = (n ^ (n >> 3)) & 7;
        bw[c] = n * 128 + (((kq >> 1) ^ key) << 4) + ((kq & 1) << 3);
    }

    // ---- fragment addresses ----
    const int lane = t & 63, wv = t >> 6;
    const int wr = wv >> 2, wc = wv & 3;         // wave tile: 64 rows x 32 cols
    const int lr = lane & 15, lg = lane >> 4;
    int abase[4], akey[4];
    #pragma unroll
    for (int mi = 0; mi < 4; mi++) {
        int m = wr * 64 + mi * 16 + lr;
        abase[mi] = m * 128;
        akey[mi] = m & 7;
    }
    int bbase[2], bkey[2];
    #pragma unroll
    for (int ni = 0; ni < 2; ni++) {
        int n = wc * 32 + ni * 16 + lr;
        bbase[ni] = n * 128;
        bkey[ni] = (n ^ (n >> 3)) & 7;
    }

    f32x4 accg[4][2] = {};
    f32x4 accu[4][2] = {};

    // prologue loads (kt = 0)
    uint4 ra0 = *(const uint4*)agp0;
    uint4 ra1 = *(const uint4*)agp1;
    f32x4 rg[4], ru[4];
    #pragma unroll
    for (int r = 0; r < 4; r++) {
        rg[r] = *(const f32x4*)(wgp + (size_t)r * D_EXP);
        ru[r] = *(const f32x4*)(wup + (size_t)r * D_EXP);
    }

    #pragma unroll 1
    for (int kt = 0; kt < D_IN / 64; kt++) {
        __syncthreads();
        *(uint4*)(smem + aw0) = ra0;
        *(uint4*)(smem + aw1) = ra1;
        #pragma unroll
        for (int c = 0; c < 4; c++) {
            ushort4 pg, pu;
            pg.x = f2bf(rg[0][c]); pg.y = f2bf(rg[1][c]); pg.z = f2bf(rg[2][c]); pg.w = f2bf(rg[3][c]);
            pu.x = f2bf(ru[0][c]); pu.y = f2bf(ru[1][c]); pu.z = f2bf(ru[2][c]); pu.w = f2bf(ru[3][c]);
            *(ushort4*)(smem + 16384 + bw[c]) = pg;
            *(ushort4*)(smem + 32768 + bw[c]) = pu;
        }
        if (kt + 1 < D_IN / 64) {
            const int kb = (kt + 1) * 64;
            ra0 = *(const uint4*)(agp0 + kb);
            ra1 = *(const uint4*)(agp1 + kb);
            #pragma unroll
            for (int r = 0; r < 4; r++) {
                rg[r] = *(const f32x4*)(wgp + (size_t)(kb + r) * D_EXP);
                ru[r] = *(const f32x4*)(wup + (size_t)(kb + r) * D_EXP);
            }
        }
        __syncthreads();

        #pragma unroll
        for (int kk = 0; kk < 2; kk++) {
            const int s = (kk << 2) + lg;
            V16 av[4], bgv[2], buv[2];
            #pragma unroll
            for (int mi = 0; mi < 4; mi++)
                av[mi].u = *(const uint4*)(smem + abase[mi] + ((s ^ akey[mi]) << 4));
            #pragma unroll
            for (int ni = 0; ni < 2; ni++) {
                bgv[ni].u = *(const uint4*)(smem + 16384 + bbase[ni] + ((s ^ bkey[ni]) << 4));
                buv[ni].u = *(const uint4*)(smem + 32768 + bbase[ni] + ((s ^ bkey[ni]) << 4));
            }
            #pragma unroll
            for (int mi = 0; mi < 4; mi++) {
                #pragma unroll
                for (int ni = 0; ni < 2; ni++) {
                    accg[mi][ni] = __builtin_amdgcn_mfma_f32_16x16x32_bf16(av[mi].b, bgv[ni].b, accg[mi][ni], 0, 0, 0);
                    accu[mi][ni] = __builtin_amdgcn_mfma_f32_16x16x32_bf16(av[mi].b, buv[ni].b, accu[mi][ni], 0, 0, 0);
                }
            }
        }
    }

    // epilogue: h = silu(g) * u -> hbuf (bf16)
    const int seg_e = seg[e];
    #pragma unroll
    for (int mi = 0; mi < 4; mi++) {
        #pragma unroll
        for (int j = 0; j < 4; j++) {
            const int rl = wr * 64 + mi * 16 + lg * 4 + j;
            if (rbase + rl < count) {
                const size_t ro = (size_t)(seg_e + rbase + rl) * D_EXP + nbase + wc * 32 + lr;
                #pragma unroll
                for (int ni = 0; ni < 2; ni++) {
                    float gv = accg[mi][ni][j], uv = accu[mi][ni][j];
                    float h = gv / (1.f + __expf(-gv)) * uv;
                    hbuf[ro + ni * 16] = f2bf(h);
                }
            }
        }
    }
}

// ---------------- GEMM2: out += (h Wd) * w, atomic scatter ----------------
__global__ __launch_bounds__(512) void gemm2_kernel(
    const unsigned short* __restrict__ hbuf,
    const float* __restrict__ wd_all,
    const int* __restrict__ rows,
    const float* __restrict__ wts,
    const int* __restrict__ cnt,
    const int* __restrict__ seg,
    float* __restrict__ out)
{
    __shared__ __align__(16) char smem[33792];  // A 16K | B 16K | tok 512 | wt 512
    const int e = blockIdx.y >> 5;
    const int rt = blockIdx.y & 31;
    const int count = cnt[e];
    const int rbase = rt << 7;
    if (rbase >= count) return;
    const int nbase = blockIdx.x << 7;
    const int t = threadIdx.x;
    const int seg_e = seg[e];

    int* tok_lds = (int*)(smem + 32768);
    float* wt_lds = (float*)(smem + 33280);
    if (t < 128) {
        int idx = rbase + t;
        if (idx > count - 1) idx = count - 1;
        tok_lds[t] = rows[(e << 12) + idx];
        wt_lds[t] = wts[(e << 12) + idx];
    }
    __syncthreads();

    // ---- A staging addresses ----
    const int a_row = t >> 3, a_slot = t & 7;
    int ar0 = rbase + a_row;      if (ar0 > count - 1) ar0 = count - 1;
    int ar1 = rbase + a_row + 64; if (ar1 > count - 1) ar1 = count - 1;
    const unsigned short* agp0 = hbuf + (size_t)(seg_e + ar0) * D_EXP + a_slot * 8;
    const unsigned short* agp1 = hbuf + (size_t)(seg_e + ar1) * D_EXP + a_slot * 8;
    const int aw0 = a_row * 128 + ((a_slot ^ (a_row & 7)) << 4);
    const int aw1 = (a_row + 64) * 128 + ((a_slot ^ (a_row & 7)) << 4);

    // ---- B staging addresses ----
    const int kq = t >> 5, bc = t & 31;
    const float* wdp = wd_all + (size_t)e * D_EXP * D_IN + (size_t)(4 * kq) * D_IN + nbase + 4 * bc;
    int bw[4];
    #pragma unroll
    for (int c = 0; c < 4; c++) {
        int n = 4 * bc + c;
        int key = (n ^ (n >> 3)) & 7;
        bw[c] = n * 128 + (((kq >> 1) ^ key) << 4) + ((kq & 1) << 3);
    }

    // ---- fragment addresses ----
    const int lane = t & 63, wv = t >> 6;
    const int wr = wv >> 2, wc = wv & 3;
    const int lr = lane & 15, lg = lane >> 4;
    int abase[4], akey[4];
    #pragma unroll
    for (int mi = 0; mi < 4; mi++) {
        int m = wr * 64 + mi * 16 + lr;
        abase[mi] = m * 128; akey[mi] = m & 7;
    }
    int bbase[2], bkey[2];
    #pragma unroll
    for (int ni = 0; ni < 2; ni++) {
        int n = wc * 32 + ni * 16 + lr;
        bbase[ni] = n * 128;
        bkey[ni] = (n ^ (n >> 3)) & 7;
    }

    f32x4 acc[4][2] = {};
    uint4 ra0 = *(const uint4*)agp0;
    uint4 ra1 = *(const uint4*)agp1;
    f32x4 rb[4];
    #pragma unroll
    for (int r = 0; r < 4; r++)
        rb[r] = *(const f32x4*)(wdp + (size_t)r * D_IN);

    #pragma unroll 1
    for (int kt = 0; kt < D_EXP / 64; kt++) {   // 48 steps
        __syncthreads();
        *(uint4*)(smem + aw0) = ra0;
        *(uint4*)(smem + aw1) = ra1;
        #pragma unroll
        for (int c = 0; c < 4; c++) {
            ushort4 p;
            p.x = f2bf(rb[0][c]); p.y = f2bf(rb[1][c]); p.z = f2bf(rb[2][c]); p.w = f2bf(rb[3][c]);
            *(ushort4*)(smem + 16384 + bw[c]) = p;
        }
        if (kt + 1 < D_EXP / 64) {
            const int kb = (kt + 1) * 64;
            ra0 = *(const uint4*)(agp0 + kb);
            ra1 = *(const uint4*)(agp1 + kb);
            #pragma unroll
            for (int r = 0; r < 4; r++)
                rb[r] = *(const f32x4*)(wdp + (size_t)(kb + r) * D_IN);
        }
        __syncthreads();

        #pragma unroll
        for (int kk = 0; kk < 2; kk++) {
            const int s = (kk << 2) + lg;
            V16 av[4], bv[2];
            #pragma unroll
            for (int mi = 0; mi < 4; mi++)
                av[mi].u = *(const uint4*)(smem + abase[mi] + ((s ^ akey[mi]) << 4));
            #pragma unroll
            for (int ni = 0; ni < 2; ni++)
                bv[ni].u = *(const uint4*)(smem + 16384 + bbase[ni] + ((s ^ bkey[ni]) << 4));
            #pragma unroll
            for (int mi = 0; mi < 4; mi++) {
                #pragma unroll
                for (int ni = 0; ni < 2; ni++)
                    acc[mi][ni] = __builtin_amdgcn_mfma_f32_16x16x32_bf16(av[mi].b, bv[ni].b, acc[mi][ni], 0, 0, 0);
            }
        }
    }

    #pragma unroll
    for (int mi = 0; mi < 4; mi++) {
        #pragma unroll
        for (int j = 0; j < 4; j++) {
            const int rl = wr * 64 + mi * 16 + lg * 4 + j;
            if (rbase + rl < count) {
                const float w = wt_lds[rl];
                const int tok = tok_lds[rl];
                #pragma unroll
                for (int ni = 0; ni < 2; ni++) {
                    const int col = nbase + wc * 32 + ni * 16 + lr;
                    atomicAdd(&out[(size_t)tok * D_IN + col], acc[mi][ni][j] * w);
                }
            }
        }
    }
}

extern "C" void kernel_launch(void* const* d_in, const int* in_sizes, int n_in,
                              void* d_out, int out_size, void* d_ws, size_t ws_size,
                              hipStream_t stream) {
    const float* x  = (const float*)d_in[0];
    const float* rw = (const float*)d_in[1];
    const float* wg = (const float*)d_in[2];
    const float* wu = (const float*)d_in[3];
    const float* wd = (const float*)d_in[4];
    const int*   ei = (const int*)d_in[5];
    float* out = (float*)d_out;
    char* ws = (char*)d_ws;

    unsigned short* xb   = (unsigned short*)(ws + WS_XB);
    int*            rows = (int*)(ws + WS_ROWS);
    float*          wts  = (float*)(ws + WS_WTS);
    int*            cnt  = (int*)(ws + WS_CNT);
    int*            seg  = (int*)(ws + WS_SEG);
    unsigned short* hbuf = (unsigned short*)(ws + WS_HBUF);

    hipMemsetAsync(d_out, 0, (size_t)out_size * sizeof(float), stream);
    route_kernel<<<1, 1024, 0, stream>>>(rw, ei, rows, wts, cnt, seg);
    cvt_x_kernel<<<(NTOK * D_IN / 4) / 256, 256, 0, stream>>>((const float4*)x, (ushort4*)xb);
    gemm1_kernel<<<dim3(D_EXP / 128, NEXP * 32), 512, 0, stream>>>(xb, wg, wu, rows, cnt, seg, hbuf);
    gemm2_kernel<<<dim3(D_IN / 128, NEXP * 32), 512, 0, stream>>>(hbuf, wd, rows, wts, cnt, seg, out);
}